// Round 4
// baseline (5644.552 us; speedup 1.0000x reference)
//
#include <hip/hip_runtime.h>
#include <hip/hip_bf16.h>

#define Mdim 8192
#define Ndim 16384
#define Ennz 2097152
#define Bsz 8
#define Jit 3
#define IMG 128

// ---- dual-mode input load: mode==1 -> fp32 storage, mode==0 -> bf16 storage ----
__device__ __forceinline__ float ldin(const void* base, int idx, int mode){
    if(mode) return ((const float*)base)[idx];
    return __bfloat162float(((const __hip_bfloat16*)base)[idx]);
}

// ---- detect storage dtype from the z buffer (d_in[3]) ----
// fp32 data read as bf16 halves -> wild exponents on mantissa words; bf16 N(0,1) never exceeds 1e4.
__global__ void ISTAConv_31318901523050_kernel(const void* zbuf, int* flag){
    __shared__ int cnt;
    if(threadIdx.x == 0) cnt = 0;
    __syncthreads();
    const __hip_bfloat16* p = (const __hip_bfloat16*)zbuf;
    int bad = 0;
    for(int i = threadIdx.x; i < 4096; i += 256){
        float v = __bfloat162float(p[i]);
        if(!(fabsf(v) < 1e4f)) bad++;       // catches NaN too
    }
    atomicAdd(&cnt, bad);
    __syncthreads();
    if(threadIdx.x == 0) flag[0] = (cnt > 64) ? 1 : 0;
}

__global__ void k_zero(float* buf, int n){
    int i = blockIdx.x*256 + threadIdx.x;
    if(i < n) buf[i] = 0.f;
}

// ---- z_cur (fp32) <- z input ----
__global__ void k_init_zcur(const void* z_in, const int* flag, float* z_cur){
    int i = blockIdx.x*256 + threadIdx.x;
    z_cur[i] = ldin(z_in, i, flag[0]);
}

// ---- zu_T[n*8+b] = z_cur[b,n]*u[b,n] ----
__global__ void k_zu(const float* z_cur, const void* u, const int* flag, float* zu_T){
    int i = blockIdx.x*256 + threadIdx.x;   // over N*8
    int n = i >> 3, b = i & 7;
    zu_T[i] = z_cur[b*Ndim + n] * ldin(u, b*Ndim + n, flag[0]);
}

// ---- resid_T[m*8+b] = y[b,m] ----
__global__ void k_init_resid(const void* y, const int* flag, float* resid_T){
    int i = blockIdx.x*256 + threadIdx.x;   // over M*8
    int m = i >> 3, b = i & 7;
    resid_T[i] = ldin(y, b*Mdim + m, flag[0]);
}

// ---- resid_T[r,:] -= val * zu_T[c,:] ----
__global__ void k_spmm1(const void* vals, const int* rows, const int* cols,
                        const int* flag, const float* zu_T, float* resid_T){
    int e = blockIdx.x*256 + threadIdx.x;
    float v = ldin(vals, e, flag[0]);
    int r = rows[e], c = cols[e];
    const float* s = zu_T + (size_t)c*8;
    float* dst = resid_T + (size_t)r*8;
    #pragma unroll
    for(int k = 0; k < 8; k++) atomicAdd(dst + k, -v * s[k]);
}

// ---- v_T[c,:] += val * resid_T[r,:] ----
__global__ void k_spmm2(const void* vals, const int* rows, const int* cols,
                        const int* flag, const float* resid_T, float* v_T){
    int e = blockIdx.x*256 + threadIdx.x;
    float v = ldin(vals, e, flag[0]);
    int r = rows[e], c = cols[e];
    const float* s = resid_T + (size_t)r*8;
    float* dst = v_T + (size_t)c*8;
    #pragma unroll
    for(int k = 0; k < 8; k++) atomicAdd(dst + k, v * s[k]);
}

// ---- per-sample L2 norm of u*v over N ----
__global__ void k_norm(const void* u, const int* flag, const float* v_T, float* ss){
    int b = blockIdx.x;
    float s = 0.f;
    for(int n = threadIdx.x; n < Ndim; n += 256){
        float t = ldin(u, b*Ndim + n, flag[0]) * v_T[n*8 + b];
        s += t*t;
    }
    __shared__ float red[256];
    red[threadIdx.x] = s; __syncthreads();
    for(int k = 128; k > 0; k >>= 1){
        if(threadIdx.x < k) red[threadIdx.x] += red[threadIdx.x + k];
        __syncthreads();
    }
    if(threadIdx.x == 0) ss[b] = sqrtf(red[0]);
}

// ---- r = z - eta/max(1,norm) * u*v ----
__global__ void k_r(const float* z_cur, const void* u, const float* v_T,
                    const float* ss, const void* etas, int j, const int* flag,
                    float* r_buf){
    int i = blockIdx.x*256 + threadIdx.x;   // B*N
    int b = i >> 14, n = i & (Ndim-1);
    float eta = ldin(etas, j, flag[0]);
    float scale = eta / fmaxf(1.0f, ss[b]);  // BCLIP = 1.0
    r_buf[i] = z_cur[i] - scale * ldin(u, i, flag[0]) * v_T[n*8 + b];
}

// ---- conv1: 1 -> 32 ch, relu ----
__global__ void k_conv1(const float* r_buf, const void* W1, int j, const int* flag,
                        float* x1){
    int i = blockIdx.x*256 + threadIdx.x;   // B*128*128*32
    int oc = i & 31;
    int w  = (i >> 5)  & 127;
    int h  = (i >> 12) & 127;
    int b  = i >> 19;
    int mode = flag[0];
    const float* img = r_buf + b*Ndim;
    float acc = 0.f;
    #pragma unroll
    for(int ky = 0; ky < 3; ky++){
        int yy = h + ky - 1; if((unsigned)yy >= 128u) continue;
        #pragma unroll
        for(int kx = 0; kx < 3; kx++){
            int xx = w + kx - 1; if((unsigned)xx >= 128u) continue;
            acc = fmaf(img[yy*IMG + xx], ldin(W1, (((j*3+ky)*3+kx)*32 + oc), mode), acc);
        }
    }
    x1[i] = fmaxf(acc, 0.f);
}

// ---- conv2: 32 -> 32 ch, relu; LDS-tiled 8x8 pixels x 32 oc, ic chunks of 16 ----
__global__ void k_conv2(const float* x1, const void* W2, int j, const int* flag,
                        float* x2){
    __shared__ float wlds[9*32*32];      // 36 KB
    __shared__ float itile[10*10*16];    // 6.4 KB
    int t = threadIdx.x;
    int blk = blockIdx.x;                // b*256 + tile
    int b = blk >> 8, tile = blk & 255;
    int oy0 = (tile >> 4) * 8, ox0 = (tile & 15) * 8;
    int mode = flag[0];

    for(int idx = t; idx < 9*32*32; idx += 256)
        wlds[idx] = ldin(W2, j*9*32*32 + idx, mode);

    int oc = t & 31, pg = t >> 5;
    float acc[8] = {0,0,0,0,0,0,0,0};

    for(int ch = 0; ch < 2; ch++){
        __syncthreads();
        for(int idx = t; idx < 10*10*16; idx += 256){
            int icl = idx & 15, p = idx >> 4;
            int yy = p/10, xx = p%10;
            int gy = oy0 + yy - 1, gx = ox0 + xx - 1;
            float val = 0.f;
            if((unsigned)gy < 128u && (unsigned)gx < 128u)
                val = x1[((b*IMG+gy)*IMG+gx)*32 + ch*16 + icl];
            itile[p*16 + icl] = val;
        }
        __syncthreads();
        for(int ky = 0; ky < 3; ky++){
            for(int kx = 0; kx < 3; kx++){
                #pragma unroll
                for(int i8 = 0; i8 < 8; i8++){
                    const float* ip = &itile[((i8+ky)*10 + (pg+kx))*16];
                    #pragma unroll
                    for(int icl = 0; icl < 16; icl++)
                        acc[i8] = fmaf(ip[icl],
                                       wlds[((ky*3+kx)*32 + ch*16 + icl)*32 + oc],
                                       acc[i8]);
                }
            }
        }
    }
    #pragma unroll
    for(int i8 = 0; i8 < 8; i8++){
        int gy = oy0 + i8, gx = ox0 + pg;
        x2[((b*IMG+gy)*IMG+gx)*32 + oc] = fmaxf(acc[i8], 0.f);
    }
}

// ---- conv3 (32->1) + residual + relu -> z_cur ----
__global__ void k_conv3(const float* x2, const void* W3, int j, const int* flag,
                        const float* r_buf, float* z_cur){
    __shared__ float it[32*325];         // 41.6 KB
    __shared__ float w3[288];
    int t = threadIdx.x;
    int blk = blockIdx.x;                // b*64 + tile (16x16 tiles)
    int b = blk >> 6, tile = blk & 63;
    int oy0 = (tile >> 3) * 16, ox0 = (tile & 7) * 16;
    int mode = flag[0];

    for(int idx = t; idx < 288; idx += 256) w3[idx] = ldin(W3, j*288 + idx, mode);
    for(int idx = t; idx < 18*18*32; idx += 256){
        int ic = idx & 31, p = idx >> 5;
        int yy = p/18, xx = p%18;
        int gy = oy0 + yy - 1, gx = ox0 + xx - 1;
        float val = 0.f;
        if((unsigned)gy < 128u && (unsigned)gx < 128u)
            val = x2[((b*IMG+gy)*IMG+gx)*32 + ic];
        it[ic*325 + p] = val;
    }
    __syncthreads();

    int py = t >> 4, px = t & 15;
    float acc = 0.f;
    for(int ic = 0; ic < 32; ic++){
        const float* row = &it[ic*325];
        #pragma unroll
        for(int ky = 0; ky < 3; ky++)
            #pragma unroll
            for(int kx = 0; kx < 3; kx++)
                acc = fmaf(row[(py+ky)*18 + (px+kx)], w3[(ky*3+kx)*32 + ic], acc);
    }
    int gy = oy0 + py, gx = ox0 + px;
    int idx = b*Ndim + gy*IMG + gx;
    z_cur[idx] = fmaxf(r_buf[idx] + acc, 0.f);
}

// ---- output: dtype follows detected input dtype; NaN/Inf sentinel = 7.0 ----
__global__ void k_out(const float* z_cur, const int* flag, void* out){
    int i = blockIdx.x*256 + threadIdx.x;
    float v = z_cur[i];
    if(!(fabsf(v) < 1e30f)) v = 7.0f;    // diagnostic sentinel for NaN/Inf
    if(flag[0]) ((float*)out)[i] = v;
    else        ((__hip_bfloat16*)out)[i] = __float2bfloat16(v);
}

extern "C" void kernel_launch(void* const* d_in, const int* in_sizes, int n_in,
                              void* d_out, int out_size, void* d_ws, size_t ws_size,
                              hipStream_t stream){
    const void* A_vals = d_in[0];
    const int* A_rows = (const int*)d_in[1];
    const int* A_cols = (const int*)d_in[2];
    const void* z_in = d_in[3];
    const void* u    = d_in[4];
    const void* y    = d_in[5];
    const void* W1   = d_in[6];
    const void* W2   = d_in[7];
    const void* W3   = d_in[8];
    const void* etas = d_in[9];

    float* ws = (float*)d_ws;
    float* z_cur   = ws;  ws += Bsz*Ndim;          // 131072
    float* r_buf   = ws;  ws += Bsz*Ndim;          // 131072
    float* zu_T    = ws;  ws += Ndim*8;            // 131072
    float* v_T     = ws;  ws += Ndim*8;            // 131072
    float* resid_T = ws;  ws += Mdim*8;            // 65536
    float* ss      = ws;  ws += 8;
    int*   flag    = (int*)ws; ws += 8;
    float* x1      = ws;  ws += (size_t)Bsz*IMG*IMG*32;   // 4.19M floats
    float* x2      = ws;                                   // 4.19M floats
    // total ~36 MB of d_ws

    ISTAConv_31318901523050_kernel<<<1, 256, 0, stream>>>(z_in, flag);
    k_init_zcur<<<Bsz*Ndim/256, 256, 0, stream>>>(z_in, flag, z_cur);
    for(int j = 0; j < Jit; j++){
        k_zu<<<Ndim*8/256, 256, 0, stream>>>(z_cur, u, flag, zu_T);
        k_init_resid<<<Mdim*8/256, 256, 0, stream>>>(y, flag, resid_T);
        k_spmm1<<<Ennz/256, 256, 0, stream>>>(A_vals, A_rows, A_cols, flag, zu_T, resid_T);
        k_zero<<<Ndim*8/256, 256, 0, stream>>>(v_T, Ndim*8);
        k_spmm2<<<Ennz/256, 256, 0, stream>>>(A_vals, A_rows, A_cols, flag, resid_T, v_T);
        k_norm<<<Bsz, 256, 0, stream>>>(u, flag, v_T, ss);
        k_r<<<Bsz*Ndim/256, 256, 0, stream>>>(z_cur, u, v_T, ss, etas, j, flag, r_buf);
        k_conv1<<<Bsz*IMG*IMG*32/256, 256, 0, stream>>>(r_buf, W1, j, flag, x1);
        k_conv2<<<Bsz*256, 256, 0, stream>>>(x1, W2, j, flag, x2);
        k_conv3<<<Bsz*64, 256, 0, stream>>>(x2, W3, j, flag, r_buf, z_cur);
    }
    k_out<<<Bsz*Ndim/256, 256, 0, stream>>>(z_cur, flag, d_out);
}

// Round 5
// 998.024 us; speedup vs baseline: 5.6557x; 5.6557x over previous
//
#include <hip/hip_runtime.h>
#include <hip/hip_bf16.h>

#define Mdim 8192
#define Ndim 16384
#define Ennz 2097152
#define Bsz 8
#define Jit 3
#define IMG 128
#define RCAP 512   // max nnz per row bucket (mean 256, std 16 -> 16 sigma)
#define CCAP 256   // max nnz per col bucket (mean 128, std 11 -> 11 sigma)

// ---- zero the 24576 bucket counters ----
__global__ void k_zeroc(int* cnt){
    int i = blockIdx.x*256 + threadIdx.x;
    cnt[i] = 0;
}

// ---- build bucketed CSR (by row) and CSC (by col) copies of A, once per launch ----
__global__ void k_build(const float* vals, const int* rows, const int* cols,
                        int* row_cnt, int* col_cnt, float2* rp, float2* cp){
    int e = blockIdx.x*256 + threadIdx.x;
    float v = vals[e];
    int r = rows[e], c = cols[e];
    int pr = atomicAdd(&row_cnt[r], 1);
    if(pr < RCAP) rp[(size_t)r*RCAP + pr] = make_float2(v, __int_as_float(c));
    int pc = atomicAdd(&col_cnt[c], 1);
    if(pc < CCAP) cp[(size_t)c*CCAP + pc] = make_float2(v, __int_as_float(r));
}

// ---- z_cur (fp32) <- z input ----
__global__ void k_init_zcur(const float* z_in, float* z_cur){
    int i = blockIdx.x*256 + threadIdx.x;
    z_cur[i] = z_in[i];
}

// ---- zu_T[n*8+b] = z_cur[b,n]*u[b,n] ----
__global__ void k_zu(const float* z_cur, const float* u, float* zu_T){
    int i = blockIdx.x*256 + threadIdx.x;   // over N*8
    int n = i >> 3, b = i & 7;
    zu_T[i] = z_cur[b*Ndim + n] * u[b*Ndim + n];
}

// ---- gather-SpMM 1: resid_T[m,:] = y[:,m] - sum_{nnz in row m} val * zu_T[col,:]
// one wave per row; lane = (ks, b): ks=nnz subgroup (8), b=batch (8)
__global__ void k_spmm1g(const float2* __restrict__ rp, const int* __restrict__ row_cnt,
                         const float* __restrict__ y, const float* __restrict__ zu_T,
                         float* __restrict__ resid_T){
    int m = (blockIdx.x*256 + threadIdx.x) >> 6;
    int lane = threadIdx.x & 63;
    int n_nz = min(row_cnt[m], RCAP);
    int b = lane & 7, ks = lane >> 3;
    const float2* base = rp + (size_t)m*RCAP;
    float acc = 0.f;
    for(int k = ks; k < n_nz; k += 8){
        float2 t = base[k];
        acc = fmaf(t.x, zu_T[__float_as_int(t.y)*8 + b], acc);
    }
    acc += __shfl_xor(acc, 8);
    acc += __shfl_xor(acc, 16);
    acc += __shfl_xor(acc, 32);
    if(ks == 0)
        resid_T[m*8 + b] = y[b*Mdim + m] - acc;
}

// ---- gather-SpMM 2: v_T[n,:] = sum_{nnz in col n} val * resid_T[row,:] ----
__global__ void k_spmm2g(const float2* __restrict__ cp, const int* __restrict__ col_cnt,
                         const float* __restrict__ resid_T, float* __restrict__ v_T){
    int n = (blockIdx.x*256 + threadIdx.x) >> 6;
    int lane = threadIdx.x & 63;
    int n_nz = min(col_cnt[n], CCAP);
    int b = lane & 7, ks = lane >> 3;
    const float2* base = cp + (size_t)n*CCAP;
    float acc = 0.f;
    for(int k = ks; k < n_nz; k += 8){
        float2 t = base[k];
        acc = fmaf(t.x, resid_T[__float_as_int(t.y)*8 + b], acc);
    }
    acc += __shfl_xor(acc, 8);
    acc += __shfl_xor(acc, 16);
    acc += __shfl_xor(acc, 32);
    if(ks == 0)
        v_T[n*8 + b] = acc;
}

// ---- per-sample L2 norm of u*v over N ----
__global__ void k_norm(const float* u, const float* v_T, float* ss){
    int b = blockIdx.x;
    float s = 0.f;
    for(int n = threadIdx.x; n < Ndim; n += 256){
        float t = u[b*Ndim + n] * v_T[n*8 + b];
        s += t*t;
    }
    __shared__ float red[256];
    red[threadIdx.x] = s; __syncthreads();
    for(int k = 128; k > 0; k >>= 1){
        if(threadIdx.x < k) red[threadIdx.x] += red[threadIdx.x + k];
        __syncthreads();
    }
    if(threadIdx.x == 0) ss[b] = sqrtf(red[0]);
}

// ---- r = z - eta/max(1,norm) * u*v ----
__global__ void k_r(const float* z_cur, const float* u, const float* v_T,
                    const float* ss, const float* etas, int j, float* r_buf){
    int i = blockIdx.x*256 + threadIdx.x;   // B*N
    int b = i >> 14, n = i & (Ndim-1);
    float scale = etas[j] / fmaxf(1.0f, ss[b]);   // BCLIP = 1.0
    r_buf[i] = z_cur[i] - scale * u[i] * v_T[n*8 + b];
}

// ---- conv1: 1 -> 32 ch, relu ----
__global__ void k_conv1(const float* __restrict__ r_buf, const float* __restrict__ W1,
                        int j, float* __restrict__ x1){
    int i = blockIdx.x*256 + threadIdx.x;   // B*128*128*32
    int oc = i & 31;
    int w  = (i >> 5)  & 127;
    int h  = (i >> 12) & 127;
    int b  = i >> 19;
    const float* img = r_buf + b*Ndim;
    float acc = 0.f;
    #pragma unroll
    for(int ky = 0; ky < 3; ky++){
        int yy = h + ky - 1; if((unsigned)yy >= 128u) continue;
        #pragma unroll
        for(int kx = 0; kx < 3; kx++){
            int xx = w + kx - 1; if((unsigned)xx >= 128u) continue;
            acc = fmaf(img[yy*IMG + xx], W1[((j*3+ky)*3+kx)*32 + oc], acc);
        }
    }
    x1[i] = fmaxf(acc, 0.f);
}

// ---- conv2: 32 -> 32 ch, relu; LDS-tiled 8x8 pixels x 32 oc, ic chunks of 16 ----
__global__ void k_conv2(const float* __restrict__ x1, const float* __restrict__ W2,
                        int j, float* __restrict__ x2){
    __shared__ float wlds[9*32*32];      // 36 KB
    __shared__ float itile[10*10*16];    // 6.4 KB
    int t = threadIdx.x;
    int blk = blockIdx.x;                // b*256 + tile
    int b = blk >> 8, tile = blk & 255;
    int oy0 = (tile >> 4) * 8, ox0 = (tile & 15) * 8;

    for(int idx = t; idx < 9*32*32; idx += 256)
        wlds[idx] = W2[j*9*32*32 + idx];

    int oc = t & 31, pg = t >> 5;
    float acc[8] = {0,0,0,0,0,0,0,0};

    for(int ch = 0; ch < 2; ch++){
        __syncthreads();
        for(int idx = t; idx < 10*10*16; idx += 256){
            int icl = idx & 15, p = idx >> 4;
            int yy = p/10, xx = p%10;
            int gy = oy0 + yy - 1, gx = ox0 + xx - 1;
            float val = 0.f;
            if((unsigned)gy < 128u && (unsigned)gx < 128u)
                val = x1[((b*IMG+gy)*IMG+gx)*32 + ch*16 + icl];
            itile[p*16 + icl] = val;
        }
        __syncthreads();
        for(int ky = 0; ky < 3; ky++){
            for(int kx = 0; kx < 3; kx++){
                #pragma unroll
                for(int i8 = 0; i8 < 8; i8++){
                    const float* ip = &itile[((i8+ky)*10 + (pg+kx))*16];
                    #pragma unroll
                    for(int icl = 0; icl < 16; icl++)
                        acc[i8] = fmaf(ip[icl],
                                       wlds[((ky*3+kx)*32 + ch*16 + icl)*32 + oc],
                                       acc[i8]);
                }
            }
        }
    }
    #pragma unroll
    for(int i8 = 0; i8 < 8; i8++){
        int gy = oy0 + i8, gx = ox0 + pg;
        x2[((b*IMG+gy)*IMG+gx)*32 + oc] = fmaxf(acc[i8], 0.f);
    }
}

// ---- conv3 (32->1) + residual + relu -> z_cur ----
__global__ void k_conv3(const float* __restrict__ x2, const float* __restrict__ W3,
                        int j, const float* __restrict__ r_buf, float* __restrict__ z_cur){
    __shared__ float it[32*325];         // 41.6 KB
    __shared__ float w3[288];
    int t = threadIdx.x;
    int blk = blockIdx.x;                // b*64 + tile (16x16 tiles)
    int b = blk >> 6, tile = blk & 63;
    int oy0 = (tile >> 3) * 16, ox0 = (tile & 7) * 16;

    for(int idx = t; idx < 288; idx += 256) w3[idx] = W3[j*288 + idx];
    for(int idx = t; idx < 18*18*32; idx += 256){
        int ic = idx & 31, p = idx >> 5;
        int yy = p/18, xx = p%18;
        int gy = oy0 + yy - 1, gx = ox0 + xx - 1;
        float val = 0.f;
        if((unsigned)gy < 128u && (unsigned)gx < 128u)
            val = x2[((b*IMG+gy)*IMG+gx)*32 + ic];
        it[ic*325 + p] = val;
    }
    __syncthreads();

    int py = t >> 4, px = t & 15;
    float acc = 0.f;
    for(int ic = 0; ic < 32; ic++){
        const float* row = &it[ic*325];
        #pragma unroll
        for(int ky = 0; ky < 3; ky++)
            #pragma unroll
            for(int kx = 0; kx < 3; kx++)
                acc = fmaf(row[(py+ky)*18 + (px+kx)], w3[(ky*3+kx)*32 + ic], acc);
    }
    int gy = oy0 + py, gx = ox0 + px;
    int idx = b*Ndim + gy*IMG + gx;
    z_cur[idx] = fmaxf(r_buf[idx] + acc, 0.f);
}

// ---- output: fp32 ----
__global__ void k_out(const float* z_cur, float* out){
    int i = blockIdx.x*256 + threadIdx.x;
    out[i] = z_cur[i];
}

extern "C" void kernel_launch(void* const* d_in, const int* in_sizes, int n_in,
                              void* d_out, int out_size, void* d_ws, size_t ws_size,
                              hipStream_t stream){
    const float* A_vals = (const float*)d_in[0];
    const int* A_rows = (const int*)d_in[1];
    const int* A_cols = (const int*)d_in[2];
    const float* z_in = (const float*)d_in[3];
    const float* u    = (const float*)d_in[4];
    const float* y    = (const float*)d_in[5];
    const float* W1   = (const float*)d_in[6];
    const float* W2   = (const float*)d_in[7];
    const float* W3   = (const float*)d_in[8];
    const float* etas = (const float*)d_in[9];

    float* ws = (float*)d_ws;
    float* z_cur   = ws;  ws += Bsz*Ndim;           // 131072
    float* r_buf   = ws;  ws += Bsz*Ndim;           // 131072
    float* zu_T    = ws;  ws += Ndim*8;             // 131072
    float* v_T     = ws;  ws += Ndim*8;             // 131072
    float* resid_T = ws;  ws += Mdim*8;             // 65536
    float* ss      = ws;  ws += 8;
    int*   row_cnt = (int*)ws; ws += Mdim;          // 8192
    int*   col_cnt = (int*)ws; ws += Ndim;          // 16384
    float* x1      = ws;  ws += (size_t)Bsz*IMG*IMG*32;   // 4.19M floats
    float* x2      = ws;  ws += (size_t)Bsz*IMG*IMG*32;   // 4.19M floats
    float2* rp = (float2*)ws; ws += (size_t)Mdim*RCAP*2;  // 32 MB
    float2* cp = (float2*)ws;                              // 32 MB
    // total ~101 MB of d_ws

    // build bucketed CSR/CSC once per launch
    k_zeroc<<<(Mdim+Ndim)/256, 256, 0, stream>>>(row_cnt);   // row_cnt & col_cnt adjacent
    k_build<<<Ennz/256, 256, 0, stream>>>(A_vals, A_rows, A_cols, row_cnt, col_cnt, rp, cp);

    k_init_zcur<<<Bsz*Ndim/256, 256, 0, stream>>>(z_in, z_cur);
    for(int j = 0; j < Jit; j++){
        k_zu<<<Ndim*8/256, 256, 0, stream>>>(z_cur, u, zu_T);
        k_spmm1g<<<Mdim/4, 256, 0, stream>>>(rp, row_cnt, y, zu_T, resid_T);
        k_spmm2g<<<Ndim/4, 256, 0, stream>>>(cp, col_cnt, resid_T, v_T);
        k_norm<<<Bsz, 256, 0, stream>>>(u, v_T, ss);
        k_r<<<Bsz*Ndim/256, 256, 0, stream>>>(z_cur, u, v_T, ss, etas, j, r_buf);
        k_conv1<<<Bsz*IMG*IMG*32/256, 256, 0, stream>>>(r_buf, W1, j, x1);
        k_conv2<<<Bsz*256, 256, 0, stream>>>(x1, W2, j, x2);
        k_conv3<<<Bsz*64, 256, 0, stream>>>(x2, W3, j, r_buf, z_cur);
    }
    k_out<<<Bsz*Ndim/256, 256, 0, stream>>>(z_cur, (float*)d_out);
}

// Round 6
// 828.299 us; speedup vs baseline: 6.8146x; 1.2049x over previous
//
#include <hip/hip_runtime.h>
#include <hip/hip_bf16.h>

#define Mdim 8192
#define Ndim 16384
#define Ennz 2097152
#define Bsz 8
#define Jit 3
#define IMG 128
#define RCAP 512   // max nnz per row bucket (mean 256)
#define CCAP 256   // max nnz per col bucket (mean 128)

// ---- zero the 24576 bucket counters (row_cnt and col_cnt are adjacent) ----
__global__ void k_zeroc(int* cnt){
    int i = blockIdx.x*256 + threadIdx.x;
    cnt[i] = 0;
}

// ---- XCD-partitioned bucketed CSR+CSC build.
// 8 groups by blockIdx&7 (round-robin block->XCD on MI355X); group g owns
// rows [g*1024,(g+1)*1024) and cols [g*2048,(g+1)*2048). Each group scans all
// of E (reads are L3-resident); scatter writes stay XCD-local so bucket lines
// accumulate in that XCD's L2 instead of 64B-amplified writebacks.
__global__ __launch_bounds__(256) void k_build(const float* __restrict__ vals,
                        const int* __restrict__ rows, const int* __restrict__ cols,
                        int* row_cnt, int* col_cnt, float2* rp, float2* cp){
    int g  = blockIdx.x & 7;
    int wg = blockIdx.x >> 3;            // 128 blocks per group
    int base = wg * (Ennz/128);          // 16384 nnz per block
    int r_lo = g*1024, c_lo = g*2048;
    for(int k = threadIdx.x; k < Ennz/128; k += 256){
        int e = base + k;
        int r = rows[e], c = cols[e];
        bool rin = ((unsigned)(r - r_lo) < 1024u);
        bool cin = ((unsigned)(c - c_lo) < 2048u);
        if(rin | cin){
            float v = vals[e];
            if(rin){
                int pr = atomicAdd(&row_cnt[r], 1);
                if(pr < RCAP) rp[(size_t)r*RCAP + pr] = make_float2(v, __int_as_float(c));
            }
            if(cin){
                int pc = atomicAdd(&col_cnt[c], 1);
                if(pc < CCAP) cp[(size_t)c*CCAP + pc] = make_float2(v, __int_as_float(r));
            }
        }
    }
}

// ---- z_cur (fp32) <- z input ----
__global__ void k_init_zcur(const float* z_in, float* z_cur){
    int i = blockIdx.x*256 + threadIdx.x;
    z_cur[i] = z_in[i];
}

// ---- zu_T[n*8+b] = z_cur[b,n]*u[b,n] ----
__global__ void k_zu(const float* z_cur, const float* u, float* zu_T){
    int i = blockIdx.x*256 + threadIdx.x;   // over N*8
    int n = i >> 3, b = i & 7;
    zu_T[i] = z_cur[b*Ndim + n] * u[b*Ndim + n];
}

// ---- gather-SpMM 1: resid_T[m,:] = y[:,m] - sum_{nnz in row m} val * zu_T[col,:] ----
__global__ void k_spmm1g(const float2* __restrict__ rp, const int* __restrict__ row_cnt,
                         const float* __restrict__ y, const float* __restrict__ zu_T,
                         float* __restrict__ resid_T){
    int m = (blockIdx.x*256 + threadIdx.x) >> 6;
    int lane = threadIdx.x & 63;
    int n_nz = min(row_cnt[m], RCAP);
    int b = lane & 7, ks = lane >> 3;
    const float2* base = rp + (size_t)m*RCAP;
    float acc = 0.f;
    for(int k = ks; k < n_nz; k += 8){
        float2 t = base[k];
        acc = fmaf(t.x, zu_T[__float_as_int(t.y)*8 + b], acc);
    }
    acc += __shfl_xor(acc, 8);
    acc += __shfl_xor(acc, 16);
    acc += __shfl_xor(acc, 32);
    if(ks == 0)
        resid_T[m*8 + b] = y[b*Mdim + m] - acc;
}

// ---- gather-SpMM 2: v_T[n,:] = sum_{nnz in col n} val * resid_T[row,:] ----
__global__ void k_spmm2g(const float2* __restrict__ cp, const int* __restrict__ col_cnt,
                         const float* __restrict__ resid_T, float* __restrict__ v_T){
    int n = (blockIdx.x*256 + threadIdx.x) >> 6;
    int lane = threadIdx.x & 63;
    int n_nz = min(col_cnt[n], CCAP);
    int b = lane & 7, ks = lane >> 3;
    const float2* base = cp + (size_t)n*CCAP;
    float acc = 0.f;
    for(int k = ks; k < n_nz; k += 8){
        float2 t = base[k];
        acc = fmaf(t.x, resid_T[__float_as_int(t.y)*8 + b], acc);
    }
    acc += __shfl_xor(acc, 8);
    acc += __shfl_xor(acc, 16);
    acc += __shfl_xor(acc, 32);
    if(ks == 0)
        v_T[n*8 + b] = acc;
}

// ---- per-sample L2 norm of u*v over N ----
__global__ void k_norm(const float* u, const float* v_T, float* ss){
    int b = blockIdx.x;
    float s = 0.f;
    for(int n = threadIdx.x; n < Ndim; n += 256){
        float t = u[b*Ndim + n] * v_T[n*8 + b];
        s += t*t;
    }
    __shared__ float red[256];
    red[threadIdx.x] = s; __syncthreads();
    for(int k = 128; k > 0; k >>= 1){
        if(threadIdx.x < k) red[threadIdx.x] += red[threadIdx.x + k];
        __syncthreads();
    }
    if(threadIdx.x == 0) ss[b] = sqrtf(red[0]);
}

// ---- r = z - eta/max(1,norm) * u*v ----
__global__ void k_r(const float* z_cur, const float* u, const float* v_T,
                    const float* ss, const float* etas, int j, float* r_buf){
    int i = blockIdx.x*256 + threadIdx.x;   // B*N
    int b = i >> 14, n = i & (Ndim-1);
    float scale = etas[j] / fmaxf(1.0f, ss[b]);   // BCLIP = 1.0
    r_buf[i] = z_cur[i] - scale * u[i] * v_T[n*8 + b];
}

// ---- fused conv1+conv2: r -> x1 (in LDS) -> x2; 8x8 pixel tile, all 32 oc ----
__global__ __launch_bounds__(256) void k_conv12(const float* __restrict__ r_buf,
                        const float* __restrict__ W1, const float* __restrict__ W2,
                        int j, float* __restrict__ x2){
    __shared__ float wlds[9*32*32];      // conv2 weights, 36 KB
    __shared__ float x1t[100*32];        // 10x10x32 x1 halo tile, 12.8 KB
    __shared__ float w1s[288];           // conv1 weights
    __shared__ float r12[144];           // 12x12 r patch
    int t = threadIdx.x;
    int blk = blockIdx.x;                // b*256 + tile
    int b = blk >> 8, tile = blk & 255;
    int oy0 = (tile >> 4) * 8, ox0 = (tile & 15) * 8;

    for(int idx = t; idx < 9*32*32; idx += 256) wlds[idx] = W2[j*9216 + idx];
    for(int idx = t; idx < 288; idx += 256)     w1s[idx]  = W1[j*288 + idx];
    if(t < 144){
        int yy = t/12, xx = t%12;
        int gy = oy0 + yy - 2, gx = ox0 + xx - 2;
        float val = 0.f;
        if((unsigned)gy < 128u && (unsigned)gx < 128u)
            val = r_buf[b*Ndim + gy*IMG + gx];
        r12[t] = val;
    }
    __syncthreads();

    // conv1 into the 10x10x32 halo tile (x1 = 0 outside the image)
    for(int idx = t; idx < 3200; idx += 256){
        int oc = idx & 31, p = idx >> 5;
        int py = p/10, px = p%10;
        int gy = oy0 + py - 1, gx = ox0 + px - 1;
        float acc = 0.f;
        if((unsigned)gy < 128u && (unsigned)gx < 128u){
            #pragma unroll
            for(int ky = 0; ky < 3; ky++)
                #pragma unroll
                for(int kx = 0; kx < 3; kx++)
                    acc = fmaf(r12[(py+ky)*12 + (px+kx)], w1s[(ky*3+kx)*32 + oc], acc);
            acc = fmaxf(acc, 0.f);
        }
        x1t[idx] = acc;
    }
    __syncthreads();

    // conv2 from LDS
    int oc = t & 31, pg = t >> 5;
    float acc[8] = {0,0,0,0,0,0,0,0};
    #pragma unroll
    for(int ch = 0; ch < 2; ch++){
        #pragma unroll
        for(int ky = 0; ky < 3; ky++){
            #pragma unroll
            for(int kx = 0; kx < 3; kx++){
                float wreg[16];
                #pragma unroll
                for(int icl = 0; icl < 16; icl++)
                    wreg[icl] = wlds[((ky*3+kx)*32 + ch*16 + icl)*32 + oc];
                #pragma unroll
                for(int i8 = 0; i8 < 8; i8++){
                    const float* ip = &x1t[((i8+ky)*10 + (pg+kx))*32 + ch*16];
                    #pragma unroll
                    for(int icl = 0; icl < 16; icl++)
                        acc[i8] = fmaf(ip[icl], wreg[icl], acc[i8]);
                }
            }
        }
    }
    #pragma unroll
    for(int i8 = 0; i8 < 8; i8++){
        int gy = oy0 + i8, gx = ox0 + pg;
        x2[((b*IMG+gy)*IMG+gx)*32 + oc] = fmaxf(acc[i8], 0.f);
    }
}

// ---- conv3 (32->1) + residual + relu -> dst (z_cur, or d_out on last iter) ----
__global__ void k_conv3(const float* __restrict__ x2, const float* __restrict__ W3,
                        int j, const float* __restrict__ r_buf, float* __restrict__ dst){
    __shared__ float it[32*325];         // 18x18 halo per ic, stride 325, 41.6 KB
    __shared__ float w3[288];
    int t = threadIdx.x;
    int blk = blockIdx.x;                // b*64 + tile (16x16 tiles)
    int b = blk >> 6, tile = blk & 63;
    int oy0 = (tile >> 3) * 16, ox0 = (tile & 7) * 16;

    for(int idx = t; idx < 288; idx += 256) w3[idx] = W3[j*288 + idx];
    for(int idx = t; idx < 18*18*32; idx += 256){
        int ic = idx & 31, p = idx >> 5;
        int yy = p/18, xx = p%18;
        int gy = oy0 + yy - 1, gx = ox0 + xx - 1;
        float val = 0.f;
        if((unsigned)gy < 128u && (unsigned)gx < 128u)
            val = x2[((b*IMG+gy)*IMG+gx)*32 + ic];
        it[ic*325 + p] = val;
    }
    __syncthreads();

    int py = t >> 4, px = t & 15;
    float acc = 0.f;
    for(int ic = 0; ic < 32; ic++){
        const float* row = &it[ic*325];
        #pragma unroll
        for(int ky = 0; ky < 3; ky++)
            #pragma unroll
            for(int kx = 0; kx < 3; kx++)
                acc = fmaf(row[(py+ky)*18 + (px+kx)], w3[(ky*3+kx)*32 + ic], acc);
    }
    int gy = oy0 + py, gx = ox0 + px;
    int idx = b*Ndim + gy*IMG + gx;
    dst[idx] = fmaxf(r_buf[idx] + acc, 0.f);
}

extern "C" void kernel_launch(void* const* d_in, const int* in_sizes, int n_in,
                              void* d_out, int out_size, void* d_ws, size_t ws_size,
                              hipStream_t stream){
    const float* A_vals = (const float*)d_in[0];
    const int* A_rows = (const int*)d_in[1];
    const int* A_cols = (const int*)d_in[2];
    const float* z_in = (const float*)d_in[3];
    const float* u    = (const float*)d_in[4];
    const float* y    = (const float*)d_in[5];
    const float* W1   = (const float*)d_in[6];
    const float* W2   = (const float*)d_in[7];
    const float* W3   = (const float*)d_in[8];
    const float* etas = (const float*)d_in[9];

    float* ws = (float*)d_ws;
    float* z_cur   = ws;  ws += Bsz*Ndim;           // 131072
    float* r_buf   = ws;  ws += Bsz*Ndim;           // 131072
    float* zu_T    = ws;  ws += Ndim*8;             // 131072
    float* v_T     = ws;  ws += Ndim*8;             // 131072
    float* resid_T = ws;  ws += Mdim*8;             // 65536
    float* ss      = ws;  ws += 8;
    int*   row_cnt = (int*)ws; ws += Mdim;          // 8192
    int*   col_cnt = (int*)ws; ws += Ndim;          // 16384
    float* x2      = ws;  ws += (size_t)Bsz*IMG*IMG*32;   // 16.8 MB
    float2* rp = (float2*)ws; ws += (size_t)Mdim*RCAP*2;  // 32 MB
    float2* cp = (float2*)ws;                              // 32 MB

    // build bucketed CSR/CSC once per launch (XCD-partitioned)
    k_zeroc<<<(Mdim+Ndim)/256, 256, 0, stream>>>(row_cnt);
    k_build<<<1024, 256, 0, stream>>>(A_vals, A_rows, A_cols, row_cnt, col_cnt, rp, cp);

    k_init_zcur<<<Bsz*Ndim/256, 256, 0, stream>>>(z_in, z_cur);
    for(int j = 0; j < Jit; j++){
        k_zu<<<Ndim*8/256, 256, 0, stream>>>(z_cur, u, zu_T);
        k_spmm1g<<<Mdim/4, 256, 0, stream>>>(rp, row_cnt, y, zu_T, resid_T);
        k_spmm2g<<<Ndim/4, 256, 0, stream>>>(cp, col_cnt, resid_T, v_T);
        k_norm<<<Bsz, 256, 0, stream>>>(u, v_T, ss);
        k_r<<<Bsz*Ndim/256, 256, 0, stream>>>(z_cur, u, v_T, ss, etas, j, r_buf);
        k_conv12<<<Bsz*256, 256, 0, stream>>>(r_buf, W1, W2, j, x2);
        float* dst = (j == Jit-1) ? (float*)d_out : z_cur;
        k_conv3<<<Bsz*64, 256, 0, stream>>>(x2, W3, j, r_buf, dst);
    }
}

// Round 7
// 815.898 us; speedup vs baseline: 6.9182x; 1.0152x over previous
//
#include <hip/hip_runtime.h>
#include <hip/hip_bf16.h>

#define Mdim 8192
#define Ndim 16384
#define Ennz 2097152
#define Bsz 8
#define Jit 3
#define IMG 128
#define RCAP 512   // max nnz per row bucket (mean 256, ~16 sigma)
#define CCAP 256   // max nnz per col bucket (mean 128, ~11 sigma)

// ---- zero the 24576 bucket counters (row_cnt and col_cnt adjacent) ----
__global__ void k_zeroc(int* cnt){
    int i = blockIdx.x*256 + threadIdx.x;
    cnt[i] = 0;
}

// ---- XCD-partitioned bucketed CSR+CSC build (unchanged from round 6) ----
__global__ __launch_bounds__(256) void k_build(const float* __restrict__ vals,
                        const int* __restrict__ rows, const int* __restrict__ cols,
                        int* row_cnt, int* col_cnt, float2* rp, float2* cp){
    int g  = blockIdx.x & 7;
    int wg = blockIdx.x >> 3;            // 128 blocks per group
    int base = wg * (Ennz/128);          // 16384 nnz per block
    int r_lo = g*1024, c_lo = g*2048;
    for(int k = threadIdx.x; k < Ennz/128; k += 256){
        int e = base + k;
        int r = rows[e], c = cols[e];
        bool rin = ((unsigned)(r - r_lo) < 1024u);
        bool cin = ((unsigned)(c - c_lo) < 2048u);
        if(rin | cin){
            float v = vals[e];
            if(rin){
                int pr = atomicAdd(&row_cnt[r], 1);
                if(pr < RCAP) rp[(size_t)r*RCAP + pr] = make_float2(v, __int_as_float(c));
            }
            if(cin){
                int pc = atomicAdd(&col_cnt[c], 1);
                if(pc < CCAP) cp[(size_t)c*CCAP + pc] = make_float2(v, __int_as_float(r));
            }
        }
    }
}

// ---- init: z_cur <- z_in, zu_T[n*8+b] <- z*u ----
__global__ void k_init(const float* __restrict__ z_in, const float* __restrict__ u,
                       float* __restrict__ z_cur, float* __restrict__ zu_T){
    int i = blockIdx.x*256 + threadIdx.x;   // over N*8 as (n,b)
    int n = i >> 3, b = i & 7;
    float z = z_in[b*Ndim + n];
    z_cur[b*Ndim + n] = z;
    zu_T[i] = z * u[b*Ndim + n];
}

// ---- gather-SpMM 1: resid_T[m,:] = y[:,m] - sum_{nnz in row m} val * zu_T[col,:] ----
__global__ void k_spmm1g(const float2* __restrict__ rp, const int* __restrict__ row_cnt,
                         const float* __restrict__ y, const float* __restrict__ zu_T,
                         float* __restrict__ resid_T){
    int m = (blockIdx.x*256 + threadIdx.x) >> 6;
    int lane = threadIdx.x & 63;
    int n_nz = min(row_cnt[m], RCAP);
    int b = lane & 7, ks = lane >> 3;
    const float2* base = rp + (size_t)m*RCAP;
    float acc = 0.f;
    for(int k = ks; k < n_nz; k += 8){
        float2 t = base[k];
        acc = fmaf(t.x, zu_T[__float_as_int(t.y)*8 + b], acc);
    }
    acc += __shfl_xor(acc, 8);
    acc += __shfl_xor(acc, 16);
    acc += __shfl_xor(acc, 32);
    if(ks == 0)
        resid_T[m*8 + b] = y[b*Mdim + m] - acc;
}

// ---- gather-SpMM 2: v_T[n,:] = sum_{nnz in col n} val * resid_T[row,:] ----
__global__ void k_spmm2g(const float2* __restrict__ cp, const int* __restrict__ col_cnt,
                         const float* __restrict__ resid_T, float* __restrict__ v_T){
    int n = (blockIdx.x*256 + threadIdx.x) >> 6;
    int lane = threadIdx.x & 63;
    int n_nz = min(col_cnt[n], CCAP);
    int b = lane & 7, ks = lane >> 3;
    const float2* base = cp + (size_t)n*CCAP;
    float acc = 0.f;
    for(int k = ks; k < n_nz; k += 8){
        float2 t = base[k];
        acc = fmaf(t.x, resid_T[__float_as_int(t.y)*8 + b], acc);
    }
    acc += __shfl_xor(acc, 8);
    acc += __shfl_xor(acc, 16);
    acc += __shfl_xor(acc, 32);
    if(ks == 0)
        v_T[n*8 + b] = acc;
}

// ---- per-sample L2 norm of u*v over N -> ss[b] ----
__global__ void k_norm(const float* __restrict__ u, const float* __restrict__ v_T,
                       float* __restrict__ ss){
    int b = blockIdx.x;
    float s = 0.f;
    for(int n = threadIdx.x; n < Ndim; n += 256){
        float t = u[b*Ndim + n] * v_T[n*8 + b];
        s += t*t;
    }
    __shared__ float red[256];
    red[threadIdx.x] = s; __syncthreads();
    for(int k = 128; k > 0; k >>= 1){
        if(threadIdx.x < k) red[threadIdx.x] += red[threadIdx.x + k];
        __syncthreads();
    }
    if(threadIdx.x == 0) ss[b] = sqrtf(red[0]);
}

// ---- fused conv1+conv2 with on-the-fly r: (z,u,v,ss) -> x1(LDS) -> x2 ----
// r = z - eta/max(1,||uv||) * u*v  computed during the 12x12 patch load.
__global__ __launch_bounds__(256) void k_conv12(const float* __restrict__ z_cur,
                        const float* __restrict__ u, const float* __restrict__ v_T,
                        const float* __restrict__ ss, const float* __restrict__ etas,
                        const float* __restrict__ W1, const float* __restrict__ W2,
                        int j, float* __restrict__ x2){
    __shared__ float wlds[9*32*32];      // conv2 weights, 36 KB
    __shared__ float x1t[100*32];        // 10x10x32 x1 halo tile, 12.8 KB
    __shared__ float w1s[288];           // conv1 weights
    __shared__ float r12[144];           // 12x12 r patch
    int t = threadIdx.x;
    int blk = blockIdx.x;                // b*256 + tile
    int b = blk >> 8, tile = blk & 255;
    int oy0 = (tile >> 4) * 8, ox0 = (tile & 15) * 8;

    for(int idx = t; idx < 9*32*32; idx += 256) wlds[idx] = W2[j*9216 + idx];
    for(int idx = t; idx < 288; idx += 256)     w1s[idx]  = W1[j*288 + idx];
    if(t < 144){
        int yy = t/12, xx = t%12;
        int gy = oy0 + yy - 2, gx = ox0 + xx - 2;
        float val = 0.f;
        if((unsigned)gy < 128u && (unsigned)gx < 128u){
            int n = gy*IMG + gx;
            int idx = b*Ndim + n;
            float scale = etas[j] / fmaxf(1.0f, ss[b]);
            val = z_cur[idx] - scale * u[idx] * v_T[n*8 + b];
        }
        r12[t] = val;
    }
    __syncthreads();

    // conv1 -> 10x10x32 halo tile (x1 = 0 outside image)
    for(int idx = t; idx < 3200; idx += 256){
        int oc = idx & 31, p = idx >> 5;
        int py = p/10, px = p%10;
        int gy = oy0 + py - 1, gx = ox0 + px - 1;
        float acc = 0.f;
        if((unsigned)gy < 128u && (unsigned)gx < 128u){
            #pragma unroll
            for(int ky = 0; ky < 3; ky++)
                #pragma unroll
                for(int kx = 0; kx < 3; kx++)
                    acc = fmaf(r12[(py+ky)*12 + (px+kx)], w1s[(ky*3+kx)*32 + oc], acc);
            acc = fmaxf(acc, 0.f);
        }
        x1t[idx] = acc;
    }
    __syncthreads();

    // conv2 from LDS, float4 (ds_read_b128) input reads
    int oc = t & 31, pg = t >> 5;
    float acc[8] = {0,0,0,0,0,0,0,0};
    #pragma unroll
    for(int ch = 0; ch < 2; ch++){
        #pragma unroll
        for(int ky = 0; ky < 3; ky++){
            #pragma unroll
            for(int kx = 0; kx < 3; kx++){
                float wreg[16];
                #pragma unroll
                for(int icl = 0; icl < 16; icl++)
                    wreg[icl] = wlds[((ky*3+kx)*32 + ch*16 + icl)*32 + oc];
                #pragma unroll
                for(int i8 = 0; i8 < 8; i8++){
                    const float4* ip4 = (const float4*)&x1t[((i8+ky)*10 + (pg+kx))*32 + ch*16];
                    float4 a0 = ip4[0], a1 = ip4[1], a2 = ip4[2], a3 = ip4[3];
                    acc[i8] = fmaf(a0.x, wreg[0],  acc[i8]);
                    acc[i8] = fmaf(a0.y, wreg[1],  acc[i8]);
                    acc[i8] = fmaf(a0.z, wreg[2],  acc[i8]);
                    acc[i8] = fmaf(a0.w, wreg[3],  acc[i8]);
                    acc[i8] = fmaf(a1.x, wreg[4],  acc[i8]);
                    acc[i8] = fmaf(a1.y, wreg[5],  acc[i8]);
                    acc[i8] = fmaf(a1.z, wreg[6],  acc[i8]);
                    acc[i8] = fmaf(a1.w, wreg[7],  acc[i8]);
                    acc[i8] = fmaf(a2.x, wreg[8],  acc[i8]);
                    acc[i8] = fmaf(a2.y, wreg[9],  acc[i8]);
                    acc[i8] = fmaf(a2.z, wreg[10], acc[i8]);
                    acc[i8] = fmaf(a2.w, wreg[11], acc[i8]);
                    acc[i8] = fmaf(a3.x, wreg[12], acc[i8]);
                    acc[i8] = fmaf(a3.y, wreg[13], acc[i8]);
                    acc[i8] = fmaf(a3.z, wreg[14], acc[i8]);
                    acc[i8] = fmaf(a3.w, wreg[15], acc[i8]);
                }
            }
        }
    }
    #pragma unroll
    for(int i8 = 0; i8 < 8; i8++){
        int gy = oy0 + i8, gx = ox0 + pg;
        x2[((b*IMG+gy)*IMG+gx)*32 + oc] = fmaxf(acc[i8], 0.f);
    }
}

// ---- conv3 (32->1) + on-the-fly r + residual relu -> dst; also zu_T for next iter ----
__global__ void k_conv3(const float* __restrict__ x2, const float* __restrict__ W3,
                        int j, const float* __restrict__ z_cur, const float* __restrict__ u,
                        const float* __restrict__ v_T, const float* __restrict__ ss,
                        const float* __restrict__ etas,
                        float* __restrict__ dst, float* __restrict__ zu_T){
    __shared__ float it[32*325];         // 18x18 halo per ic, stride 325, 41.6 KB
    __shared__ float w3[288];
    int t = threadIdx.x;
    int blk = blockIdx.x;                // b*64 + tile (16x16 tiles)
    int b = blk >> 6, tile = blk & 63;
    int oy0 = (tile >> 3) * 16, ox0 = (tile & 7) * 16;

    for(int idx = t; idx < 288; idx += 256) w3[idx] = W3[j*288 + idx];
    for(int idx = t; idx < 18*18*32; idx += 256){
        int ic = idx & 31, p = idx >> 5;
        int yy = p/18, xx = p%18;
        int gy = oy0 + yy - 1, gx = ox0 + xx - 1;
        float val = 0.f;
        if((unsigned)gy < 128u && (unsigned)gx < 128u)
            val = x2[((b*IMG+gy)*IMG+gx)*32 + ic];
        it[ic*325 + p] = val;
    }
    __syncthreads();

    int py = t >> 4, px = t & 15;
    float acc = 0.f;
    for(int ic = 0; ic < 32; ic++){
        const float* row = &it[ic*325];
        #pragma unroll
        for(int ky = 0; ky < 3; ky++)
            #pragma unroll
            for(int kx = 0; kx < 3; kx++)
                acc = fmaf(row[(py+ky)*18 + (px+kx)], w3[(ky*3+kx)*32 + ic], acc);
    }
    int gy = oy0 + py, gx = ox0 + px;
    int n = gy*IMG + gx;
    int idx = b*Ndim + n;
    float uu = u[idx];
    float scale = etas[j] / fmaxf(1.0f, ss[b]);
    float r = z_cur[idx] - scale * uu * v_T[n*8 + b];
    float z_new = fmaxf(r + acc, 0.f);
    dst[idx] = z_new;
    zu_T[n*8 + b] = z_new * uu;          // for next iteration's spmm1
}

extern "C" void kernel_launch(void* const* d_in, const int* in_sizes, int n_in,
                              void* d_out, int out_size, void* d_ws, size_t ws_size,
                              hipStream_t stream){
    const float* A_vals = (const float*)d_in[0];
    const int* A_rows = (const int*)d_in[1];
    const int* A_cols = (const int*)d_in[2];
    const float* z_in = (const float*)d_in[3];
    const float* u    = (const float*)d_in[4];
    const float* y    = (const float*)d_in[5];
    const float* W1   = (const float*)d_in[6];
    const float* W2   = (const float*)d_in[7];
    const float* W3   = (const float*)d_in[8];
    const float* etas = (const float*)d_in[9];

    float* ws = (float*)d_ws;
    float* z_cur   = ws;  ws += Bsz*Ndim;           // 131072
    float* zu_T    = ws;  ws += Ndim*8;             // 131072
    float* v_T     = ws;  ws += Ndim*8;             // 131072
    float* resid_T = ws;  ws += Mdim*8;             // 65536
    float* ss      = ws;  ws += 8;
    int*   row_cnt = (int*)ws; ws += Mdim;          // 8192
    int*   col_cnt = (int*)ws; ws += Ndim;          // 16384
    float* x2      = ws;  ws += (size_t)Bsz*IMG*IMG*32;   // 16.8 MB
    float2* rp = (float2*)ws; ws += (size_t)Mdim*RCAP*2;  // 32 MB
    float2* cp = (float2*)ws;                              // 32 MB

    k_zeroc<<<(Mdim+Ndim)/256, 256, 0, stream>>>(row_cnt);
    k_build<<<1024, 256, 0, stream>>>(A_vals, A_rows, A_cols, row_cnt, col_cnt, rp, cp);
    k_init<<<Bsz*Ndim/256, 256, 0, stream>>>(z_in, u, z_cur, zu_T);

    for(int j = 0; j < Jit; j++){
        k_spmm1g<<<Mdim/4, 256, 0, stream>>>(rp, row_cnt, y, zu_T, resid_T);
        k_spmm2g<<<Ndim/4, 256, 0, stream>>>(cp, col_cnt, resid_T, v_T);
        k_norm<<<Bsz, 256, 0, stream>>>(u, v_T, ss);
        k_conv12<<<Bsz*256, 256, 0, stream>>>(z_cur, u, v_T, ss, etas, W1, W2, j, x2);
        float* dst = (j == Jit-1) ? (float*)d_out : z_cur;
        k_conv3<<<Bsz*64, 256, 0, stream>>>(x2, W3, j, z_cur, u, v_T, ss, etas, dst, zu_T);
    }
}

// Round 8
// 541.756 us; speedup vs baseline: 10.4190x; 1.5060x over previous
//
#include <hip/hip_runtime.h>
#include <hip/hip_bf16.h>

#define Mdim 8192
#define Ndim 16384
#define Ennz 2097152
#define Bsz 8
#define Jit 3
#define IMG 128
#define RCAP 512
#define CCAP 256

typedef __attribute__((ext_vector_type(8))) short bf8_t;   // 8 bf16 = 4 VGPRs
typedef __attribute__((ext_vector_type(4))) float f4_t;

__device__ __forceinline__ short f2b(float f){
    __hip_bfloat16 h = __float2bfloat16(f);
    return *reinterpret_cast<short*>(&h);
}

// ---- zero the 24576 bucket counters ----
__global__ void k_zeroc(int* cnt){
    int i = blockIdx.x*256 + threadIdx.x;
    cnt[i] = 0;
}

// ---- XCD-partitioned bucketed CSR+CSC build (unchanged) ----
__global__ __launch_bounds__(256) void k_build(const float* __restrict__ vals,
                        const int* __restrict__ rows, const int* __restrict__ cols,
                        int* row_cnt, int* col_cnt, float2* rp, float2* cp){
    int g  = blockIdx.x & 7;
    int wg = blockIdx.x >> 3;
    int base = wg * (Ennz/128);
    int r_lo = g*1024, c_lo = g*2048;
    for(int k = threadIdx.x; k < Ennz/128; k += 256){
        int e = base + k;
        int r = rows[e], c = cols[e];
        bool rin = ((unsigned)(r - r_lo) < 1024u);
        bool cin = ((unsigned)(c - c_lo) < 2048u);
        if(rin | cin){
            float v = vals[e];
            if(rin){
                int pr = atomicAdd(&row_cnt[r], 1);
                if(pr < RCAP) rp[(size_t)r*RCAP + pr] = make_float2(v, __int_as_float(c));
            }
            if(cin){
                int pc = atomicAdd(&col_cnt[c], 1);
                if(pc < CCAP) cp[(size_t)c*CCAP + pc] = make_float2(v, __int_as_float(r));
            }
        }
    }
}

// ---- init: z_cur <- z_in, zu_T[n*8+b] <- z*u ----
__global__ void k_init(const float* __restrict__ z_in, const float* __restrict__ u,
                       float* __restrict__ z_cur, float* __restrict__ zu_T){
    int i = blockIdx.x*256 + threadIdx.x;
    int n = i >> 3, b = i & 7;
    float z = z_in[b*Ndim + n];
    z_cur[b*Ndim + n] = z;
    zu_T[i] = z * u[b*Ndim + n];
}

// ---- gather-SpMM 1 (+ zero ssq for this iteration's norm) ----
__global__ void k_spmm1g(const float2* __restrict__ rp, const int* __restrict__ row_cnt,
                         const float* __restrict__ y, const float* __restrict__ zu_T,
                         float* __restrict__ resid_T, float* __restrict__ ssq){
    if(blockIdx.x == 0 && threadIdx.x < 8) ssq[threadIdx.x] = 0.f;
    int m = (blockIdx.x*256 + threadIdx.x) >> 6;
    int lane = threadIdx.x & 63;
    int n_nz = min(row_cnt[m], RCAP);
    int b = lane & 7, ks = lane >> 3;
    const float2* base = rp + (size_t)m*RCAP;
    float acc = 0.f;
    for(int k = ks; k < n_nz; k += 8){
        float2 t = base[k];
        acc = fmaf(t.x, zu_T[__float_as_int(t.y)*8 + b], acc);
    }
    acc += __shfl_xor(acc, 8);
    acc += __shfl_xor(acc, 16);
    acc += __shfl_xor(acc, 32);
    if(ks == 0)
        resid_T[m*8 + b] = y[b*Mdim + m] - acc;
}

// ---- gather-SpMM 2 ----
__global__ void k_spmm2g(const float2* __restrict__ cp, const int* __restrict__ col_cnt,
                         const float* __restrict__ resid_T, float* __restrict__ v_T){
    int n = (blockIdx.x*256 + threadIdx.x) >> 6;
    int lane = threadIdx.x & 63;
    int n_nz = min(col_cnt[n], CCAP);
    int b = lane & 7, ks = lane >> 3;
    const float2* base = cp + (size_t)n*CCAP;
    float acc = 0.f;
    for(int k = ks; k < n_nz; k += 8){
        float2 t = base[k];
        acc = fmaf(t.x, resid_T[__float_as_int(t.y)*8 + b], acc);
    }
    acc += __shfl_xor(acc, 8);
    acc += __shfl_xor(acc, 16);
    acc += __shfl_xor(acc, 32);
    if(ks == 0)
        v_T[n*8 + b] = acc;
}

// ---- parallel partial sum of (u*v)^2 per sample -> ssq[b] (128 blocks) ----
__global__ __launch_bounds__(256) void k_normp(const float* __restrict__ u,
                        const float* __restrict__ v_T, float* __restrict__ ssq){
    int t = threadIdx.x;
    float s = 0.f;
    #pragma unroll
    for(int c = 0; c < 4; c++){
        int idx = c*32768 + blockIdx.x*256 + t;   // over N*8
        int n = idx >> 3, b = idx & 7;
        float tv = u[b*Ndim + n] * v_T[idx];
        s = fmaf(tv, tv, s);
    }
    s += __shfl_xor(s, 8);
    s += __shfl_xor(s, 16);
    s += __shfl_xor(s, 32);
    if(((t & 63) >> 3) == 0) atomicAdd(&ssq[t & 7], s);
}

// ---- fused conv1 (VALU) + conv2 (MFMA bf16): r on-the-fly -> x1(LDS bf16) -> x2 ----
__global__ __launch_bounds__(256) void k_conv12(const float* __restrict__ z_cur,
                        const float* __restrict__ u, const float* __restrict__ v_T,
                        const float* __restrict__ ssq, const float* __restrict__ etas,
                        const float* __restrict__ W1, const float* __restrict__ W2,
                        int j, float* __restrict__ x2){
    __shared__ short w2t[9*32*40];       // [kk][oc][ic], ic padded to 40 — 23 KB
    __shared__ short x1t[100*40];        // [pixel][ic], padded — 8 KB
    __shared__ float w1s[288];
    __shared__ float r12[144];
    int t = threadIdx.x;
    int blk = blockIdx.x;
    int b = blk >> 8, tile = blk & 255;
    int oy0 = (tile >> 4) * 8, ox0 = (tile & 15) * 8;

    // stage W2 transposed to bf16 [kk][oc][ic]
    for(int idx = t; idx < 9216; idx += 256){
        int kk = idx >> 10, rem = idx & 1023;
        int ic = rem >> 5, oc = rem & 31;
        w2t[(kk*32 + oc)*40 + ic] = f2b(W2[j*9216 + idx]);
    }
    for(int idx = t; idx < 288; idx += 256) w1s[idx] = W1[j*288 + idx];
    if(t < 144){
        int yy = t/12, xx = t%12;
        int gy = oy0 + yy - 2, gx = ox0 + xx - 2;
        float val = 0.f;
        if((unsigned)gy < 128u && (unsigned)gx < 128u){
            int n = gy*IMG + gx;
            int idx = b*Ndim + n;
            float scale = etas[j] / fmaxf(1.0f, sqrtf(ssq[b]));
            val = z_cur[idx] - scale * u[idx] * v_T[n*8 + b];
        }
        r12[t] = val;
    }
    __syncthreads();

    // conv1 -> x1t (bf16), 2 adjacent oc per thread packed as one b32 write
    for(int idx = t; idx < 1600; idx += 256){
        int ocp = idx & 15, p = idx >> 4;          // oc pair, pixel 0..99
        int py = p/10, px = p%10;
        int gy = oy0 + py - 1, gx = ox0 + px - 1;
        float a0 = 0.f, a1 = 0.f;
        if((unsigned)gy < 128u && (unsigned)gx < 128u){
            #pragma unroll
            for(int ky = 0; ky < 3; ky++)
                #pragma unroll
                for(int kx = 0; kx < 3; kx++){
                    float rv = r12[(py+ky)*12 + (px+kx)];
                    a0 = fmaf(rv, w1s[(ky*3+kx)*32 + 2*ocp],     a0);
                    a1 = fmaf(rv, w1s[(ky*3+kx)*32 + 2*ocp + 1], a1);
                }
            a0 = fmaxf(a0, 0.f); a1 = fmaxf(a1, 0.f);
        }
        unsigned pack = (unsigned short)f2b(a0) | ((unsigned)(unsigned short)f2b(a1) << 16);
        ((unsigned*)x1t)[p*20 + ocp] = pack;
    }
    __syncthreads();

    // conv2 as MFMA: wave w owns pixels 16w..16w+15; N=32 split into 2 halves
    int wv = t >> 6, lane = t & 63;
    int m = lane & 15, q = lane >> 4;
    int p = 16*wv + m;
    int py = p >> 3, px = p & 7;
    f4_t acc0 = {0.f,0.f,0.f,0.f}, acc1 = {0.f,0.f,0.f,0.f};
    #pragma unroll
    for(int kk = 0; kk < 9; kk++){
        int ky = kk/3, kx = kk%3;
        bf8_t a  = *(const bf8_t*)&x1t[((py+ky)*10 + (px+kx))*40 + q*8];
        bf8_t b0 = *(const bf8_t*)&w2t[(kk*32 + m)*40 + q*8];
        bf8_t b1 = *(const bf8_t*)&w2t[(kk*32 + 16 + m)*40 + q*8];
        acc0 = __builtin_amdgcn_mfma_f32_16x16x32_bf16(a, b0, acc0, 0, 0, 0);
        acc1 = __builtin_amdgcn_mfma_f32_16x16x32_bf16(a, b1, acc1, 0, 0, 0);
    }
    // D: col = lane&15 (oc), row = q*4+reg (pixel within 16)
    #pragma unroll
    for(int r = 0; r < 4; r++){
        int prow = 16*wv + q*4 + r;
        int gy = oy0 + (prow >> 3), gx = ox0 + (prow & 7);
        float* dst = &x2[((b*IMG+gy)*IMG+gx)*32];
        dst[m]      = fmaxf(acc0[r], 0.f);
        dst[m + 16] = fmaxf(acc1[r], 0.f);
    }
}

// ---- conv3 (32->1) + on-the-fly r + residual relu -> dst; zu_T for next iter ----
__global__ void k_conv3(const float* __restrict__ x2, const float* __restrict__ W3,
                        int j, const float* __restrict__ z_cur, const float* __restrict__ u,
                        const float* __restrict__ v_T, const float* __restrict__ ssq,
                        const float* __restrict__ etas,
                        float* __restrict__ dst, float* __restrict__ zu_T){
    __shared__ float it[32*325];
    __shared__ float w3[288];
    int t = threadIdx.x;
    int blk = blockIdx.x;
    int b = blk >> 6, tile = blk & 63;
    int oy0 = (tile >> 3) * 16, ox0 = (tile & 7) * 16;

    for(int idx = t; idx < 288; idx += 256) w3[idx] = W3[j*288 + idx];
    for(int idx = t; idx < 18*18*32; idx += 256){
        int ic = idx & 31, p = idx >> 5;
        int yy = p/18, xx = p%18;
        int gy = oy0 + yy - 1, gx = ox0 + xx - 1;
        float val = 0.f;
        if((unsigned)gy < 128u && (unsigned)gx < 128u)
            val = x2[((b*IMG+gy)*IMG+gx)*32 + ic];
        it[ic*325 + p] = val;
    }
    __syncthreads();

    int py = t >> 4, px = t & 15;
    float acc = 0.f;
    for(int ic = 0; ic < 32; ic++){
        const float* row = &it[ic*325];
        #pragma unroll
        for(int ky = 0; ky < 3; ky++)
            #pragma unroll
            for(int kx = 0; kx < 3; kx++)
                acc = fmaf(row[(py+ky)*18 + (px+kx)], w3[(ky*3+kx)*32 + ic], acc);
    }
    int gy = oy0 + py, gx = ox0 + px;
    int n = gy*IMG + gx;
    int idx = b*Ndim + n;
    float uu = u[idx];
    float scale = etas[j] / fmaxf(1.0f, sqrtf(ssq[b]));
    float r = z_cur[idx] - scale * uu * v_T[n*8 + b];
    float z_new = fmaxf(r + acc, 0.f);
    dst[idx] = z_new;
    zu_T[n*8 + b] = z_new * uu;
}

extern "C" void kernel_launch(void* const* d_in, const int* in_sizes, int n_in,
                              void* d_out, int out_size, void* d_ws, size_t ws_size,
                              hipStream_t stream){
    const float* A_vals = (const float*)d_in[0];
    const int* A_rows = (const int*)d_in[1];
    const int* A_cols = (const int*)d_in[2];
    const float* z_in = (const float*)d_in[3];
    const float* u    = (const float*)d_in[4];
    const float* y    = (const float*)d_in[5];
    const float* W1   = (const float*)d_in[6];
    const float* W2   = (const float*)d_in[7];
    const float* W3   = (const float*)d_in[8];
    const float* etas = (const float*)d_in[9];

    float* ws = (float*)d_ws;
    float* z_cur   = ws;  ws += Bsz*Ndim;
    float* zu_T    = ws;  ws += Ndim*8;
    float* v_T     = ws;  ws += Ndim*8;
    float* resid_T = ws;  ws += Mdim*8;
    float* ssq     = ws;  ws += 8;
    int*   row_cnt = (int*)ws; ws += Mdim;
    int*   col_cnt = (int*)ws; ws += Ndim;
    float* x2      = ws;  ws += (size_t)Bsz*IMG*IMG*32;
    float2* rp = (float2*)ws; ws += (size_t)Mdim*RCAP*2;
    float2* cp = (float2*)ws;

    k_zeroc<<<(Mdim+Ndim)/256, 256, 0, stream>>>(row_cnt);
    k_build<<<1024, 256, 0, stream>>>(A_vals, A_rows, A_cols, row_cnt, col_cnt, rp, cp);
    k_init<<<Bsz*Ndim/256, 256, 0, stream>>>(z_in, u, z_cur, zu_T);

    for(int j = 0; j < Jit; j++){
        k_spmm1g<<<Mdim/4, 256, 0, stream>>>(rp, row_cnt, y, zu_T, resid_T, ssq);
        k_spmm2g<<<Ndim/4, 256, 0, stream>>>(cp, col_cnt, resid_T, v_T);
        k_normp<<<128, 256, 0, stream>>>(u, v_T, ssq);
        k_conv12<<<Bsz*256, 256, 0, stream>>>(z_cur, u, v_T, ssq, etas, W1, W2, j, x2);
        float* dst = (j == Jit-1) ? (float*)d_out : z_cur;
        k_conv3<<<Bsz*64, 256, 0, stream>>>(x2, W3, j, z_cur, u, v_T, ssq, etas, dst, zu_T);
    }
}

// Round 9
// 503.031 us; speedup vs baseline: 11.2211x; 1.0770x over previous
//
#include <hip/hip_runtime.h>
#include <hip/hip_bf16.h>

#define Mdim 8192
#define Ndim 16384
#define Ennz 2097152
#define Bsz 8
#define Jit 3
#define IMG 128
#define RCAP 512
#define CCAP 256

typedef __attribute__((ext_vector_type(8))) short bf8_t;   // 8 bf16 = 4 VGPRs
typedef __attribute__((ext_vector_type(4))) float f4_t;

__device__ __forceinline__ short f2b(float f){
    __hip_bfloat16 h = __float2bfloat16(f);
    return *reinterpret_cast<short*>(&h);
}

// ---- zero the 24576 bucket counters ----
__global__ void k_zeroc(int* cnt){
    int i = blockIdx.x*256 + threadIdx.x;
    cnt[i] = 0;
}

// ---- XCD-partitioned bucketed CSR+CSC build (unchanged; next round's target) ----
__global__ __launch_bounds__(256) void k_build(const float* __restrict__ vals,
                        const int* __restrict__ rows, const int* __restrict__ cols,
                        int* row_cnt, int* col_cnt, float2* rp, float2* cp){
    int g  = blockIdx.x & 7;
    int wg = blockIdx.x >> 3;
    int base = wg * (Ennz/128);
    int r_lo = g*1024, c_lo = g*2048;
    for(int k = threadIdx.x; k < Ennz/128; k += 256){
        int e = base + k;
        int r = rows[e], c = cols[e];
        bool rin = ((unsigned)(r - r_lo) < 1024u);
        bool cin = ((unsigned)(c - c_lo) < 2048u);
        if(rin | cin){
            float v = vals[e];
            if(rin){
                int pr = atomicAdd(&row_cnt[r], 1);
                if(pr < RCAP) rp[(size_t)r*RCAP + pr] = make_float2(v, __int_as_float(c));
            }
            if(cin){
                int pc = atomicAdd(&col_cnt[c], 1);
                if(pc < CCAP) cp[(size_t)c*CCAP + pc] = make_float2(v, __int_as_float(r));
            }
        }
    }
}

// ---- init: z_cur <- z_in, zu_T[n*8+b] <- z*u ----
__global__ void k_init(const float* __restrict__ z_in, const float* __restrict__ u,
                       float* __restrict__ z_cur, float* __restrict__ zu_T){
    int i = blockIdx.x*256 + threadIdx.x;
    int n = i >> 3, b = i & 7;
    float z = z_in[b*Ndim + n];
    z_cur[b*Ndim + n] = z;
    zu_T[i] = z * u[b*Ndim + n];
}

// ---- gather-SpMM 1 (+ zero ssq for this iteration's norm) ----
__global__ void k_spmm1g(const float2* __restrict__ rp, const int* __restrict__ row_cnt,
                         const float* __restrict__ y, const float* __restrict__ zu_T,
                         float* __restrict__ resid_T, float* __restrict__ ssq){
    if(blockIdx.x == 0 && threadIdx.x < 8) ssq[threadIdx.x] = 0.f;
    int m = (blockIdx.x*256 + threadIdx.x) >> 6;
    int lane = threadIdx.x & 63;
    int n_nz = min(row_cnt[m], RCAP);
    int b = lane & 7, ks = lane >> 3;
    const float2* base = rp + (size_t)m*RCAP;
    float acc = 0.f;
    for(int k = ks; k < n_nz; k += 8){
        float2 t = base[k];
        acc = fmaf(t.x, zu_T[__float_as_int(t.y)*8 + b], acc);
    }
    acc += __shfl_xor(acc, 8);
    acc += __shfl_xor(acc, 16);
    acc += __shfl_xor(acc, 32);
    if(ks == 0)
        resid_T[m*8 + b] = y[b*Mdim + m] - acc;
}

// ---- gather-SpMM 2 ----
__global__ void k_spmm2g(const float2* __restrict__ cp, const int* __restrict__ col_cnt,
                         const float* __restrict__ resid_T, float* __restrict__ v_T){
    int n = (blockIdx.x*256 + threadIdx.x) >> 6;
    int lane = threadIdx.x & 63;
    int n_nz = min(col_cnt[n], CCAP);
    int b = lane & 7, ks = lane >> 3;
    const float2* base = cp + (size_t)n*CCAP;
    float acc = 0.f;
    for(int k = ks; k < n_nz; k += 8){
        float2 t = base[k];
        acc = fmaf(t.x, resid_T[__float_as_int(t.y)*8 + b], acc);
    }
    acc += __shfl_xor(acc, 8);
    acc += __shfl_xor(acc, 16);
    acc += __shfl_xor(acc, 32);
    if(ks == 0)
        v_T[n*8 + b] = acc;
}

// ---- parallel partial sum of (u*v)^2 per sample -> ssq[b] ----
__global__ __launch_bounds__(256) void k_normp(const float* __restrict__ u,
                        const float* __restrict__ v_T, float* __restrict__ ssq){
    int t = threadIdx.x;
    float s = 0.f;
    #pragma unroll
    for(int c = 0; c < 4; c++){
        int idx = c*32768 + blockIdx.x*256 + t;
        int n = idx >> 3, b = idx & 7;
        float tv = u[b*Ndim + n] * v_T[idx];
        s = fmaf(tv, tv, s);
    }
    s += __shfl_xor(s, 8);
    s += __shfl_xor(s, 16);
    s += __shfl_xor(s, 32);
    if(((t & 63) >> 3) == 0) atomicAdd(&ssq[t & 7], s);
}

// ---- fully fused conv1+conv2+conv3: r(14x14) -> x1(12x12x32) -> x2(10x10x32) -> z(8x8)
// conv1 VALU; conv2 & conv3 MFMA bf16 (conv3 uses N=16, only col 0 consumed).
__global__ __launch_bounds__(256) void k_conv123(
        const float* __restrict__ z_cur, const float* __restrict__ u,
        const float* __restrict__ v_T, const float* __restrict__ ssq,
        const float* __restrict__ etas, const float* __restrict__ W1,
        const float* __restrict__ W2, const float* __restrict__ W3,
        int j, float* __restrict__ dst, float* __restrict__ zu_T){
    __shared__ short w2t[9*32*40];       // [kk][oc][ic] bf16, ic padded to 40 — 23 KB
    __shared__ short x1t[144*40];        // 12x12 px × 32 ic bf16 — 11.5 KB
    __shared__ short x2t[100*40];        // 10x10 px × 32 ic bf16 — 8 KB
    __shared__ float w1s[288];
    __shared__ short w3b[288];           // [kk][ic] bf16
    __shared__ float r14[196];           // 14x14 r patch
    int t = threadIdx.x;
    int blk = blockIdx.x;
    int bb = blk >> 8, tile = blk & 255;
    int oy0 = (tile >> 4)*8, ox0 = (tile & 15)*8;

    for(int idx = t; idx < 9216; idx += 256){
        int kk = idx >> 10, rem = idx & 1023;
        int ic = rem >> 5, oc = rem & 31;
        w2t[(kk*32 + oc)*40 + ic] = f2b(W2[j*9216 + idx]);
    }
    for(int idx = t; idx < 288; idx += 256){
        w1s[idx] = W1[j*288 + idx];
        w3b[idx] = f2b(W3[j*288 + idx]);
    }
    if(t < 196){
        int yy = t/14, xx = t%14;
        int gy = oy0 + yy - 3, gx = ox0 + xx - 3;
        float val = 0.f;
        if((unsigned)gy < 128u && (unsigned)gx < 128u){
            int n = gy*IMG + gx;
            int idx = bb*Ndim + n;
            float scale = etas[j] / fmaxf(1.0f, sqrtf(ssq[bb]));
            val = z_cur[idx] - scale * u[idx] * v_T[n*8 + bb];
        }
        r14[t] = val;
    }
    __syncthreads();

    // conv1 -> x1t (bf16), 2 adjacent oc per thread packed as one b32 write
    for(int idx = t; idx < 2304; idx += 256){
        int ocp = idx & 15, p = idx >> 4;          // 144 pixels, 16 oc-pairs
        int py = p/12, px = p%12;
        int gy = oy0 + py - 2, gx = ox0 + px - 2;
        float a0 = 0.f, a1 = 0.f;
        if((unsigned)gy < 128u && (unsigned)gx < 128u){
            #pragma unroll
            for(int ky = 0; ky < 3; ky++)
                #pragma unroll
                for(int kx = 0; kx < 3; kx++){
                    float rv = r14[(py+ky)*14 + (px+kx)];
                    a0 = fmaf(rv, w1s[(ky*3+kx)*32 + 2*ocp],     a0);
                    a1 = fmaf(rv, w1s[(ky*3+kx)*32 + 2*ocp + 1], a1);
                }
            a0 = fmaxf(a0, 0.f); a1 = fmaxf(a1, 0.f);
        }
        unsigned pack = (unsigned short)f2b(a0) | ((unsigned)(unsigned short)f2b(a1) << 16);
        ((unsigned*)x1t)[p*20 + ocp] = pack;
    }
    __syncthreads();

    int wv = t >> 6, lane = t & 63, mm = lane & 15, q = lane >> 4;

    // conv2 MFMA -> x2t (100 pixels in two 64-slot rounds); off-image pixels zeroed
    #pragma unroll
    for(int rnd = 0; rnd < 2; rnd++){
        int p = rnd*64 + wv*16 + mm;
        int pp = min(p, 99);
        int py2 = pp/10, px2 = pp%10;
        f4_t acc0 = {0.f,0.f,0.f,0.f}, acc1 = {0.f,0.f,0.f,0.f};
        #pragma unroll
        for(int kk = 0; kk < 9; kk++){
            int ky = kk/3, kx = kk%3;
            bf8_t a  = *(const bf8_t*)&x1t[((py2+ky)*12 + (px2+kx))*40 + q*8];
            bf8_t b0 = *(const bf8_t*)&w2t[(kk*32 + mm)*40 + q*8];
            bf8_t b1 = *(const bf8_t*)&w2t[(kk*32 + 16 + mm)*40 + q*8];
            acc0 = __builtin_amdgcn_mfma_f32_16x16x32_bf16(a, b0, acc0, 0, 0, 0);
            acc1 = __builtin_amdgcn_mfma_f32_16x16x32_bf16(a, b1, acc1, 0, 0, 0);
        }
        #pragma unroll
        for(int reg = 0; reg < 4; reg++){
            int pw = rnd*64 + wv*16 + q*4 + reg;   // D: row=q*4+reg, col=mm
            if(pw < 100){
                int py = pw/10, px = pw%10;
                int gy = oy0 + py - 1, gx = ox0 + px - 1;
                bool in = ((unsigned)gy < 128u) && ((unsigned)gx < 128u);
                x2t[pw*40 + mm]      = in ? f2b(fmaxf(acc0[reg], 0.f)) : (short)0;
                x2t[pw*40 + mm + 16] = in ? f2b(fmaxf(acc1[reg], 0.f)) : (short)0;
            }
        }
    }
    __syncthreads();

    // conv3 MFMA: 64 output pixels = 4 waves × 16 rows; only n=0 column used
    int p3 = wv*16 + mm;
    int py3 = p3 >> 3, px3 = p3 & 7;
    f4_t acc = {0.f,0.f,0.f,0.f};
    #pragma unroll
    for(int kk = 0; kk < 9; kk++){
        int ky = kk/3, kx = kk%3;
        bf8_t a = *(const bf8_t*)&x2t[((py3+ky)*10 + (px3+kx))*40 + q*8];
        bf8_t bf;
        #pragma unroll
        for(int jj = 0; jj < 8; jj++)
            bf[jj] = (mm == 0) ? w3b[kk*32 + q*8 + jj] : (short)0;
        acc = __builtin_amdgcn_mfma_f32_16x16x32_bf16(a, bf, acc, 0, 0, 0);
    }
    if(mm == 0){
        #pragma unroll
        for(int reg = 0; reg < 4; reg++){
            int po = wv*16 + q*4 + reg;
            int py = po >> 3, px = po & 7;
            int gy = oy0 + py, gx = ox0 + px;
            int n = gy*IMG + gx;
            int idx = bb*Ndim + n;
            float r = r14[(py+3)*14 + (px+3)];
            float znew = fmaxf(r + acc[reg], 0.f);
            dst[idx] = znew;
            zu_T[n*8 + bb] = znew * u[idx];
        }
    }
}

extern "C" void kernel_launch(void* const* d_in, const int* in_sizes, int n_in,
                              void* d_out, int out_size, void* d_ws, size_t ws_size,
                              hipStream_t stream){
    const float* A_vals = (const float*)d_in[0];
    const int* A_rows = (const int*)d_in[1];
    const int* A_cols = (const int*)d_in[2];
    const float* z_in = (const float*)d_in[3];
    const float* u    = (const float*)d_in[4];
    const float* y    = (const float*)d_in[5];
    const float* W1   = (const float*)d_in[6];
    const float* W2   = (const float*)d_in[7];
    const float* W3   = (const float*)d_in[8];
    const float* etas = (const float*)d_in[9];

    float* ws = (float*)d_ws;
    float* z_cur   = ws;  ws += Bsz*Ndim;
    float* zu_T    = ws;  ws += Ndim*8;
    float* v_T     = ws;  ws += Ndim*8;
    float* resid_T = ws;  ws += Mdim*8;
    float* ssq     = ws;  ws += 8;
    int*   row_cnt = (int*)ws; ws += Mdim;
    int*   col_cnt = (int*)ws; ws += Ndim;
    float2* rp = (float2*)ws; ws += (size_t)Mdim*RCAP*2;
    float2* cp = (float2*)ws;

    k_zeroc<<<(Mdim+Ndim)/256, 256, 0, stream>>>(row_cnt);
    k_build<<<1024, 256, 0, stream>>>(A_vals, A_rows, A_cols, row_cnt, col_cnt, rp, cp);
    k_init<<<Bsz*Ndim/256, 256, 0, stream>>>(z_in, u, z_cur, zu_T);

    for(int j = 0; j < Jit; j++){
        k_spmm1g<<<Mdim/4, 256, 0, stream>>>(rp, row_cnt, y, zu_T, resid_T, ssq);
        k_spmm2g<<<Ndim/4, 256, 0, stream>>>(cp, col_cnt, resid_T, v_T);
        k_normp<<<128, 256, 0, stream>>>(u, v_T, ssq);
        float* dst = (j == Jit-1) ? (float*)d_out : z_cur;
        k_conv123<<<Bsz*256, 256, 0, stream>>>(z_cur, u, v_T, ssq, etas,
                                               W1, W2, W3, j, dst, zu_T);
    }
}